// Round 2
// baseline (339.136 us; speedup 1.0000x reference)
//
#include <hip/hip_runtime.h>

// ValenceConstraint R2: replace device-scope atomics (32B fabric txn each,
// 130us) with per-block-exclusive histogram slices + workgroup-scope atomics
// that complete in the XCD's L2. Slices are packed 4x u8 counts per u32.
//
// ws layout: [accum f32 @0 | pad to 64 | slices C*W u32 | penalty N f32]
// Output: d_out = [h_new (N*D fp32) | constraint_loss (1 fp32)].

__device__ __forceinline__ float max_valence(int z) {
    switch (z) {
        case 1:  return 1.0f;
        case 6:  return 4.0f;
        case 7:  return 3.0f;
        case 8:  return 2.0f;
        case 9:  return 1.0f;
        case 15: return 5.0f;
        case 16: return 6.0f;
        case 17: return 7.0f;
        default: return 4.0f;
    }
}

__device__ __forceinline__ void slice_inc(unsigned int* slice, int a) {
    // packed byte counter: word a>>2, byte a&3. Workgroup scope: this slice
    // is touched by exactly one workgroup, so L2-local RMW is correct.
    __hip_atomic_fetch_add(&slice[((unsigned)a) >> 2],
                           1u << ((((unsigned)a) & 3u) << 3),
                           __ATOMIC_RELAXED, __HIP_MEMORY_SCOPE_WORKGROUP);
}

__global__ void vc_count_sliced(const int* __restrict__ row, int E, int chunk,
                                unsigned int* __restrict__ slices, int W) {
    const int b = blockIdx.x;
    unsigned int* slice = slices + (size_t)b * W;
    const int start = b * chunk;               // chunk is a multiple of 4
    const int end   = min(start + chunk, E);
    if (start >= E) return;
    const int nq = (end - start) >> 2;
    const int4* q = reinterpret_cast<const int4*>(row + start);
    for (int i = threadIdx.x; i < nq; i += blockDim.x) {
        int4 r = q[i];
        slice_inc(slice, r.x);
        slice_inc(slice, r.y);
        slice_inc(slice, r.z);
        slice_inc(slice, r.w);
    }
    for (int i = start + (nq << 2) + threadIdx.x; i < end; i += blockDim.x)
        slice_inc(slice, row[i]);
}

// Sum C packed slices per word (byte totals < 255: no carry), compute
// violation + penalty per atom, block-reduce violation sum into accum.
__global__ void vc_reduce_sliced(const unsigned int* __restrict__ slices,
                                 int C, int W,
                                 const int* __restrict__ types, int N,
                                 float* __restrict__ penalty,
                                 float* __restrict__ accum) {
    const int w = blockIdx.x * blockDim.x + threadIdx.x;
    float vsum = 0.0f;
    if (w < W) {
        unsigned int s = 0;
        const unsigned int* p = slices + w;
        int c = 0;
        for (; c + 4 <= C; c += 4) {
            s += p[(size_t)(c + 0) * W];
            s += p[(size_t)(c + 1) * W];
            s += p[(size_t)(c + 2) * W];
            s += p[(size_t)(c + 3) * W];
        }
        for (; c < C; ++c) s += p[(size_t)c * W];

        const int base = w * 4;
        float pen[4];
        #pragma unroll
        for (int k = 0; k < 4; ++k) {
            int a = base + k;
            float pv = 1.0f;
            if (a < N) {
                float cnt  = (float)((s >> (k * 8)) & 0xffu);
                float viol = fmaxf(cnt - max_valence(types[a]), 0.0f);
                vsum += viol;
                pv = (viol > 0.0f) ? (1.0f - viol * 0.1f) : 1.0f;
            }
            pen[k] = pv;
        }
        if (base + 3 < N) {
            *reinterpret_cast<float4*>(penalty + base) =
                make_float4(pen[0], pen[1], pen[2], pen[3]);
        } else {
            for (int k = 0; k < 4 && base + k < N; ++k) penalty[base + k] = pen[k];
        }
    }
    // wave64 reduce then block reduce, one device atomic per block
    #pragma unroll
    for (int off = 32; off > 0; off >>= 1) vsum += __shfl_down(vsum, off, 64);
    __shared__ float sh[4];
    int lane = threadIdx.x & 63;
    int wv = threadIdx.x >> 6;
    if (lane == 0) sh[wv] = vsum;
    __syncthreads();
    if (threadIdx.x == 0) atomicAdd(accum, sh[0] + sh[1] + sh[2] + sh[3]);
}

__global__ void vc_loss_kernel(const float* __restrict__ accum,
                               float* __restrict__ out_loss, float scale) {
    *out_loss = (*accum) * scale;
}

// Streaming scale: 4 float4 quads per thread; penalty gathered per-row
// (64 consecutive threads share a row for D=256 -> broadcast).
__global__ void vc_scale(const float4* __restrict__ h,
                         const float* __restrict__ penalty,
                         float4* __restrict__ out,
                         int nquads, int qpr, int qshift) {
    int t = blockIdx.x * (blockDim.x * 4) + threadIdx.x;
    #pragma unroll
    for (int k = 0; k < 4; ++k, t += blockDim.x) {
        if (t < nquads) {
            int row = (qshift >= 0) ? (t >> qshift) : (t / qpr);
            float p = penalty[row];
            float4 x = h[t];
            x.x *= p; x.y *= p; x.z *= p; x.w *= p;
            out[t] = x;
        }
    }
}

extern "C" void kernel_launch(void* const* d_in, const int* in_sizes, int n_in,
                              void* d_out, int out_size, void* d_ws, size_t ws_size,
                              hipStream_t stream) {
    const float* h          = (const float*)d_in[0];
    const int*   edge_index = (const int*)d_in[1];
    const int*   atom_types = (const int*)d_in[2];

    const int N = in_sizes[2];
    const int D = in_sizes[0] / N;   // 256
    const int E = in_sizes[1] / 2;   // rows are the first E entries

    // words per slice, 16B-aligned so penalty (after slices) is float4-aligned
    const int W = (((N + 3) / 4) + 3) & ~3;

    // pick slice count C to fit ws: 64 + C*W*4 + N*4 <= ws_size
    int C = 256;
    {
        long long avail = (long long)ws_size - 64 - (long long)N * 4;
        long long cmax  = avail / ((long long)W * 4);
        if (cmax < C) C = (int)cmax;
        if (C > 256) C = 256;
        if (C < 1)   C = 1;   // degenerate fallback: single block does all edges
    }

    float*        accum   = (float*)d_ws;
    unsigned int* slices  = (unsigned int*)((char*)d_ws + 64);
    float*        penalty = (float*)((char*)d_ws + 64 + (size_t)C * W * 4);

    float* out_h    = (float*)d_out;
    float* out_loss = out_h + (size_t)N * D;

    // zero accum + slices (ws is re-poisoned 0xAA before every timed call)
    hipMemsetAsync(d_ws, 0, 64 + (size_t)C * W * 4, stream);

    // 1) per-block-exclusive packed histograms, L2-local atomics
    {
        int chunk = ((E + C - 1) / C + 3) & ~3;
        vc_count_sliced<<<C, 1024, 0, stream>>>(edge_index, E, chunk, slices, W);
    }

    // 2) merge slices -> violation, penalty, loss-sum
    {
        int blocks = (W + 255) / 256;
        vc_reduce_sliced<<<blocks, 256, 0, stream>>>(slices, C, W, atom_types, N,
                                                     penalty, accum);
    }

    // 3) loss = (sum / N) * 0.05
    vc_loss_kernel<<<1, 1, 0, stream>>>(accum, out_loss, 0.05f / (float)N);

    // 4) h_new = h * penalty
    {
        int nquads = (N * D) / 4;
        int qpr = D / 4;
        int qshift = (qpr > 0 && (qpr & (qpr - 1)) == 0) ? __builtin_ctz(qpr) : -1;
        int blocks = (nquads + 1023) / 1024;
        vc_scale<<<blocks, 256, 0, stream>>>(
            (const float4*)h, penalty, (float4*)out_h, nquads, qpr, qshift);
    }
}

// Round 4
// 249.703 us; speedup vs baseline: 1.3582x; 1.3582x over previous
//
#include <hip/hip_runtime.h>

// ValenceConstraint R4 (= R3 with compile fix): LDS histograms (DS atomics,
// CU-local) instead of global atomics (R1/R2: 3.2M global atomic RMWs ->
// ~99 MB HBM write traffic, ~122us). Each of C=64 blocks histograms its edge
// chunk into LDS u16 counts over 1/4 of the atom range per pass (50 KB LDS,
// overflow-proof: per-block count <= chunk < 65536), dumps to a private
// global slice with streaming stores, then a merge kernel sums slices
// (unpacked to u32 -> no overflow), computes penalty + violation sum.
// Fix vs R3: nontemporal builtins need native vector types, not
// HIP_vector_type -> use ext_vector_type(4) float.
//
// ws: [accum f32 @0 | pad 64 | slices C*W2 u32 | penalty N f32]
// out: [h_new (N*D f32) | loss (1 f32)]

typedef float floatx4 __attribute__((ext_vector_type(4)));

__device__ __forceinline__ float max_valence(int z) {
    switch (z) {
        case 1:  return 1.0f;
        case 6:  return 4.0f;
        case 7:  return 3.0f;
        case 8:  return 2.0f;
        case 9:  return 1.0f;
        case 15: return 5.0f;
        case 16: return 6.0f;
        case 17: return 7.0f;
        default: return 4.0f;
    }
}

#define VC_WR 12504   // LDS u32 words per range pass (~50 KB)

// grid = C blocks x 1024. Block b owns edges [b*chunk, b*chunk+chunk).
// NR range passes of RA atoms each; WR = RA/2 u32 words (2 x u16 per word).
__global__ void vc_count_lds(const int* __restrict__ row, int E, int chunk,
                             unsigned int* __restrict__ slices,
                             int RA, int NR, int WR, int W2) {
    __shared__ unsigned int lds[VC_WR];
    const int b = blockIdx.x;
    const int start = b * chunk;              // chunk is a multiple of 4
    if (start >= E) return;
    const int end = min(start + chunk, E);
    const int nq  = (end - start) >> 2;
    const int4* q = reinterpret_cast<const int4*>(row + start);
    unsigned int* slice = slices + (size_t)b * W2;

    for (int r = 0; r < NR; ++r) {
        const int lo = r * RA;
        // zero this pass's LDS histogram
        for (int i = threadIdx.x; i < WR; i += blockDim.x) lds[i] = 0;
        __syncthreads();
        // scatter: u16-packed LDS atomics (stay in the CU's DS pipe)
        for (int i = threadIdx.x; i < nq; i += blockDim.x) {
            int4 e = q[i];
            int a;
            a = e.x - lo; if ((unsigned)a < (unsigned)RA)
                atomicAdd(&lds[a >> 1], 1u << ((a & 1) << 4));
            a = e.y - lo; if ((unsigned)a < (unsigned)RA)
                atomicAdd(&lds[a >> 1], 1u << ((a & 1) << 4));
            a = e.z - lo; if ((unsigned)a < (unsigned)RA)
                atomicAdd(&lds[a >> 1], 1u << ((a & 1) << 4));
            a = e.w - lo; if ((unsigned)a < (unsigned)RA)
                atomicAdd(&lds[a >> 1], 1u << ((a & 1) << 4));
        }
        for (int i = start + (nq << 2) + threadIdx.x; i < end; i += blockDim.x) {
            int a = row[i] - lo;
            if ((unsigned)a < (unsigned)RA)
                atomicAdd(&lds[a >> 1], 1u << ((a & 1) << 4));
        }
        __syncthreads();
        // dump histogram to this block's global slice (streaming, coalesced)
        for (int i = threadIdx.x; i < WR; i += blockDim.x)
            __builtin_nontemporal_store(lds[i], &slice[r * WR + i]);
        __syncthreads();
    }
}

// One thread per u32 word (2 atoms): sum C slices with u16 unpack (u32
// accumulate -> overflow-free), violation + penalty, block-reduce loss sum.
__global__ void vc_merge(const unsigned int* __restrict__ slices,
                         int C, int W2,
                         const int* __restrict__ types, int N,
                         float* __restrict__ penalty,
                         float* __restrict__ accum) {
    const int w = blockIdx.x * blockDim.x + threadIdx.x;
    float vsum = 0.0f;
    if (w < W2) {
        unsigned int s0 = 0, s1 = 0;
        const unsigned int* p = slices + w;
        for (int c = 0; c < C; ++c) {
            unsigned int x = p[(size_t)c * W2];
            s0 += x & 0xffffu;
            s1 += x >> 16;
        }
        const int a0 = w * 2;
        float pen0 = 1.0f, pen1 = 1.0f;
        if (a0 < N) {
            float v = fmaxf((float)s0 - max_valence(types[a0]), 0.0f);
            vsum += v;
            pen0 = (v > 0.0f) ? (1.0f - v * 0.1f) : 1.0f;
        }
        if (a0 + 1 < N) {
            float v = fmaxf((float)s1 - max_valence(types[a0 + 1]), 0.0f);
            vsum += v;
            pen1 = (v > 0.0f) ? (1.0f - v * 0.1f) : 1.0f;
        }
        if (a0 + 1 < N)
            *reinterpret_cast<float2*>(penalty + a0) = make_float2(pen0, pen1);
        else if (a0 < N)
            penalty[a0] = pen0;
    }
    #pragma unroll
    for (int off = 32; off > 0; off >>= 1) vsum += __shfl_down(vsum, off, 64);
    __shared__ float sh[4];
    int lane = threadIdx.x & 63;
    int wv = threadIdx.x >> 6;
    if (lane == 0) sh[wv] = vsum;
    __syncthreads();
    if (threadIdx.x == 0) atomicAdd(accum, sh[0] + sh[1] + sh[2] + sh[3]);
}

// Streaming scale; thread 0 of block 0 also writes the loss (accum is ready:
// prior dispatch completed). Nontemporal h/out stream keeps L2 for penalty.
__global__ void vc_scale(const floatx4* __restrict__ h,
                         const float* __restrict__ penalty,
                         floatx4* __restrict__ out,
                         int nquads, int qpr, int qshift,
                         const float* __restrict__ accum,
                         float* __restrict__ out_loss, float lscale) {
    if (blockIdx.x == 0 && threadIdx.x == 0) *out_loss = (*accum) * lscale;
    int t = blockIdx.x * (blockDim.x * 4) + threadIdx.x;
    #pragma unroll
    for (int k = 0; k < 4; ++k, t += blockDim.x) {
        if (t < nquads) {
            int rowi = (qshift >= 0) ? (t >> qshift) : (t / qpr);
            float p = penalty[rowi];
            floatx4 x = __builtin_nontemporal_load(&h[t]);
            x *= p;
            __builtin_nontemporal_store(x, &out[t]);
        }
    }
}

extern "C" void kernel_launch(void* const* d_in, const int* in_sizes, int n_in,
                              void* d_out, int out_size, void* d_ws, size_t ws_size,
                              hipStream_t stream) {
    const float* h          = (const float*)d_in[0];
    const int*   edge_index = (const int*)d_in[1];
    const int*   atom_types = (const int*)d_in[2];

    const int N = in_sizes[2];
    const int D = in_sizes[0] / N;   // 256
    const int E = in_sizes[1] / 2;   // rows are the first E entries

    // range/slice geometry: NR passes of RA atoms; RA even; RA/2 <= VC_WR
    const int NR = 4;
    int RA = ((N + NR - 1) / NR + 1) & ~1;        // even
    if (RA / 2 > VC_WR) RA = VC_WR * 2;           // (N<=100k always fits)
    const int WR = RA / 2;
    const int W2 = NR * WR;                        // u32 words per slice

    int C = 64;
    {
        long long avail = (long long)ws_size - 64 - (long long)N * 4;
        long long cmax  = avail / ((long long)W2 * 4);
        if (cmax < C) C = (int)cmax;
        if (C < 1) C = 1;
    }

    float*        accum   = (float*)d_ws;
    unsigned int* slices  = (unsigned int*)((char*)d_ws + 64);
    float*        penalty = (float*)((char*)d_ws + 64 + (size_t)C * W2 * 4);

    float* out_h    = (float*)d_out;
    float* out_loss = out_h + (size_t)N * D;

    (void)hipMemsetAsync(d_ws, 0, 64, stream);   // just accum

    // 1) LDS histograms -> per-block slices
    {
        int chunk = ((E + C - 1) / C + 3) & ~3;
        vc_count_lds<<<C, 1024, 0, stream>>>(edge_index, E, chunk, slices,
                                             RA, NR, WR, W2);
    }

    // 2) merge -> penalty + violation sum
    {
        int blocks = (W2 + 255) / 256;
        vc_merge<<<blocks, 256, 0, stream>>>(slices, C, W2, atom_types, N,
                                             penalty, accum);
    }

    // 3) loss (inside scale) + h_new = h * penalty
    {
        int nquads = (N * D) / 4;
        int qpr = D / 4;
        int qshift = (qpr > 0 && (qpr & (qpr - 1)) == 0) ? __builtin_ctz(qpr) : -1;
        int blocks = (nquads + 1023) / 1024;
        vc_scale<<<blocks, 256, 0, stream>>>(
            (const floatx4*)h, penalty, (floatx4*)out_h, nquads, qpr, qshift,
            accum, out_loss, 0.05f / (float)N);
    }
}